// Round 5
// baseline (334.637 us; speedup 1.0000x reference)
//
#include <hip/hip_runtime.h>
#include <hip/hip_fp16.h>
#include <stdint.h>

#define M_TOT 16384   // B*S = 4*4096
#define N_TOT 2048
#define K_TOT 2048

#define BM 128
#define BN 128
#define BK 64
#define NBN (N_TOT / BN)   // 16

typedef int v4i  __attribute__((ext_vector_type(4)));
typedef int v16i __attribute__((ext_vector_type(16)));

__device__ __forceinline__ void async_load16(const signed char* g, signed char* l) {
    __builtin_amdgcn_global_load_lds(
        (const __attribute__((address_space(1))) void*)g,
        (__attribute__((address_space(3))) void*)l,
        16, 0, 0);
}

// ---------------- weight repack: int32 (harness upload) -> int8 ----------------
// weight values are in [-127,127]; low byte of each int32 is the exact int8.
__global__ __launch_bounds__(256) void pack_w_kernel(
    const int* __restrict__ wi, signed char* __restrict__ wo)
{
    const int idx = blockIdx.x * 256 + threadIdx.x;   // one per 4 elements
    const int4 v = ((const int4*)wi)[idx];
    const int packed = (v.x & 0xff) | ((v.y & 0xff) << 8) |
                       ((v.z & 0xff) << 16) | (v.w << 24);
    ((int*)wo)[idx] = packed;
}

// ---------------- per-token int8 quantization ----------------
// one block (256 threads) per token row of 2048 f32
__global__ __launch_bounds__(256) void quant_kernel(
    const float* __restrict__ x,
    signed char* __restrict__ q,
    float* __restrict__ scales)
{
    const int row = blockIdx.x;
    const int t = threadIdx.x;
    const float4* xr = (const float4*)(x + (size_t)row * K_TOT);
    float4 v0 = xr[t];          // cols t*4 .. t*4+3
    float4 v1 = xr[t + 256];    // cols 1024 + t*4 ..

    float m = fmaxf(fmaxf(fabsf(v0.x), fabsf(v0.y)), fmaxf(fabsf(v0.z), fabsf(v0.w)));
    m = fmaxf(m, fmaxf(fmaxf(fabsf(v1.x), fabsf(v1.y)), fmaxf(fabsf(v1.z), fabsf(v1.w))));
    #pragma unroll
    for (int off = 32; off >= 1; off >>= 1)
        m = fmaxf(m, __shfl_xor(m, off));
    __shared__ float red[4];
    if ((t & 63) == 0) red[t >> 6] = m;
    __syncthreads();
    m = fmaxf(fmaxf(red[0], red[1]), fmaxf(red[2], red[3]));

    const float scale = fmaxf(m, 1e-7f) / 127.0f;
    if (t == 0) scales[row] = scale;

    // quantize 8 values, exact IEEE div + rintf (matches jnp.round half-even)
    int p0 = 0, p1 = 0;
    {
        float a0[4] = {v0.x, v0.y, v0.z, v0.w};
        float a1[4] = {v1.x, v1.y, v1.z, v1.w};
        #pragma unroll
        for (int j = 0; j < 4; ++j) {
            float r0 = fminf(fmaxf(rintf(a0[j] / scale), -128.f), 127.f);
            float r1 = fminf(fmaxf(rintf(a1[j] / scale), -128.f), 127.f);
            p0 |= ((int)r0 & 0xff) << (8 * j);
            p1 |= ((int)r1 & 0xff) << (8 * j);
        }
    }
    int* qrow = (int*)(q + (size_t)row * K_TOT);
    qrow[t] = p0;
    qrow[t + 256] = p1;
}

// ---------------- int8 GEMM + fused dequant epilogue ----------------
// C[m,n] = fp16( i32acc(q[m,:] . w[n,:]) * in_scale[m] * w_scale[n] + bias[n] )
// 128x128 tile, BK=64, 4 waves (2x2 of 64x64), mfma_i32_32x32x32_i8.
// LDS layout [row][64B of k] with slot swizzle: phys_slot = log_slot ^ ((row>>1)&3).
// global_load_lds writes linear LDS; swizzle is applied to the GLOBAL source slot
// (rule #21: linear dest + inverse-swizzled source + swizzled read).
__global__ __launch_bounds__(256) void gemm_kernel(
    const signed char* __restrict__ q,
    const signed char* __restrict__ w,
    const float* __restrict__ scales,
    const float* __restrict__ w_scale,
    const float* __restrict__ bias,
    float* __restrict__ out)
{
    __shared__ __align__(16) signed char As[BM * BK];  // 8 KiB
    __shared__ __align__(16) signed char Bs[BN * BK];  // 8 KiB

    const int tid  = threadIdx.x;
    const int lane = tid & 63;
    const int wid  = tid >> 6;
    const int l31  = lane & 31;
    const int l5   = lane >> 5;
    const int wrow = wid >> 1;   // 0..1
    const int wcol = wid & 1;    // 0..1

    const int bm = blockIdx.x / NBN;
    const int bn = blockIdx.x % NBN;
    const size_t arow0 = (size_t)bm * BM;
    const size_t brow0 = (size_t)bn * BN;

    // staging: 512 chunks of 16B per tile; thread t covers chunk t and 256+t
    const int r0 = tid >> 2;          // rows 0..63
    const int r1 = 64 + (tid >> 2);   // rows 64..127
    const int sp = tid & 3;           // physical slot
    const int sl0 = sp ^ ((r0 >> 1) & 3);  // logical (global) slot
    const int sl1 = sp ^ ((r1 >> 1) & 3);

    const signed char* ga0 = q + (arow0 + r0) * K_TOT + sl0 * 16;
    const signed char* ga1 = q + (arow0 + r1) * K_TOT + sl1 * 16;
    const signed char* gb0 = w + (brow0 + r0) * K_TOT + sl0 * 16;
    const signed char* gb1 = w + (brow0 + r1) * K_TOT + sl1 * 16;
    signed char* la0 = As + (size_t)tid * 16;
    signed char* la1 = As + (size_t)(256 + tid) * 16;
    signed char* lb0 = Bs + (size_t)tid * 16;
    signed char* lb1 = Bs + (size_t)(256 + tid) * 16;

    // loop-invariant fragment read offsets (swizzled)
    int a_off[2][2], b_off[2][2];
    #pragma unroll
    for (int mi = 0; mi < 2; ++mi) {
        int rrow = wrow * 64 + mi * 32 + l31;
        #pragma unroll
        for (int ki = 0; ki < 2; ++ki) {
            int slot = (ki * 2 + l5) ^ ((rrow >> 1) & 3);
            a_off[mi][ki] = rrow * 64 + slot * 16;
        }
    }
    #pragma unroll
    for (int ni = 0; ni < 2; ++ni) {
        int rrow = wcol * 64 + ni * 32 + l31;
        #pragma unroll
        for (int ki = 0; ki < 2; ++ki) {
            int slot = (ki * 2 + l5) ^ ((rrow >> 1) & 3);
            b_off[ni][ki] = rrow * 64 + slot * 16;
        }
    }

    v16i acc[2][2];
    #pragma unroll
    for (int i = 0; i < 2; ++i)
        #pragma unroll
        for (int j = 0; j < 2; ++j)
            acc[i][j] = (v16i)(0);

    for (int kt = 0; kt < K_TOT / BK; ++kt) {
        const int k0 = kt * BK;
        async_load16(ga0 + k0, la0);
        async_load16(ga1 + k0, la1);
        async_load16(gb0 + k0, lb0);
        async_load16(gb1 + k0, lb1);
        asm volatile("s_waitcnt vmcnt(0)" ::: "memory");
        __syncthreads();

        v4i a[2][2], b[2][2];
        #pragma unroll
        for (int mi = 0; mi < 2; ++mi)
            #pragma unroll
            for (int ki = 0; ki < 2; ++ki)
                a[mi][ki] = *(const v4i*)(As + a_off[mi][ki]);
        #pragma unroll
        for (int ni = 0; ni < 2; ++ni)
            #pragma unroll
            for (int ki = 0; ki < 2; ++ki)
                b[ni][ki] = *(const v4i*)(Bs + b_off[ni][ki]);

        #pragma unroll
        for (int ki = 0; ki < 2; ++ki)
            #pragma unroll
            for (int mi = 0; mi < 2; ++mi)
                #pragma unroll
                for (int ni = 0; ni < 2; ++ni)
                    acc[mi][ni] = __builtin_amdgcn_mfma_i32_32x32x32_i8(
                        a[mi][ki], b[ni][ki], acc[mi][ni], 0, 0, 0);

        __syncthreads();
    }

    // epilogue: C/D layout for 32x32: col = lane&31, row = (r&3) + 8*(r>>2) + 4*(lane>>5)
    const int gm0 = bm * BM + wrow * 64;
    const int gn0 = bn * BN + wcol * 64;
    #pragma unroll
    for (int ni = 0; ni < 2; ++ni) {
        const int col = gn0 + ni * 32 + l31;
        const float wsc = w_scale[col];
        const float bb  = bias[col];
        #pragma unroll
        for (int mi = 0; mi < 2; ++mi) {
            const int rb = gm0 + mi * 32 + 4 * l5;
            #pragma unroll
            for (int r2 = 0; r2 < 16; ++r2) {
                const int row = rb + (r2 & 3) + 8 * (r2 >> 2);
                const float si = scales[row];
                float val = fmaf((float)acc[mi][ni][r2], si * wsc, bb);
                out[(size_t)row * N_TOT + col] = __half2float(__float2half_rn(val));
            }
        }
    }
}

extern "C" void kernel_launch(void* const* d_in, const int* in_sizes, int n_in,
                              void* d_out, int out_size, void* d_ws, size_t ws_size,
                              hipStream_t stream) {
    const float* x        = (const float*)d_in[0];
    const int*   weight_i = (const int*)d_in[1];     // int8 values uploaded as int32
    const float* w_scale  = (const float*)d_in[2];
    const float* bias     = (const float*)d_in[3];
    float*       out      = (float*)d_out;

    signed char* q      = (signed char*)d_ws;                                  // 32 MiB
    float*       scales = (float*)((char*)d_ws + (size_t)M_TOT * K_TOT);       // 64 KiB
    signed char* wp     = (signed char*)d_ws + (size_t)M_TOT * K_TOT + 65536;  // 4 MiB

    pack_w_kernel<<<(N_TOT * K_TOT / 4) / 256, 256, 0, stream>>>(weight_i, wp);
    quant_kernel<<<M_TOT, 256, 0, stream>>>(x, q, scales);
    gemm_kernel<<<(M_TOT / BM) * (N_TOT / BN), 256, 0, stream>>>(
        q, wp, scales, w_scale, bias, out);
}